// Round 14
// baseline (265.913 us; speedup 1.0000x reference)
//
#include <hip/hip_runtime.h>
#include <hip/hip_bf16.h>

// Problem: B=8, T=2048, D_IN=D_EMB=D_OUT=1024
#define B_DIM 8
#define T_DIM 2048
#define E_DIM 1024

typedef __attribute__((ext_vector_type(8))) short short8;
typedef __attribute__((ext_vector_type(4))) float f32x4;
typedef __attribute__((ext_vector_type(4))) int int4v;

__device__ __forceinline__ unsigned short f2bf(float f) {
  union { float f; unsigned u; } v; v.f = f;
  unsigned r = v.u + 0x7fffu + ((v.u >> 16) & 1u);
  return (unsigned short)(r >> 16);
}
__device__ __forceinline__ float bf2f(unsigned short u) {
  union { unsigned u; float f; } v; v.u = ((unsigned)u) << 16;
  return v.f;
}
__device__ __forceinline__ signed char q8(float f, float scale) {
  int q = __float2int_rn(f * scale);
  q = q > 127 ? 127 : (q < -127 ? -127 : q);
  return (signed char)q;
}

__device__ __forceinline__ void async16(const void* g, void* l) {
  __builtin_amdgcn_global_load_lds(
      (const __attribute__((address_space(1))) unsigned int*)g,
      (__attribute__((address_space(3))) unsigned int*)l, 16, 0, 0);
}

__device__ __forceinline__ void storeC(float* p, float v) { *p = v; }
__device__ __forceinline__ void storeC(unsigned short* p, float v) { *p = f2bf(v); }
__device__ __forceinline__ void storeC(signed char* p, float v) { *p = (signed char)(int)v; }

// quantization constants
#define QX 31.75f               /* x:  127/4    */
#define QY 1814.2857f           /* Y:  127/0.07 */
#define QP 15.875f              /* P:  127/8    */
#define KDQ_LOGIT 1.7359973e-5f /* (0.07/127)*(4/127) */
#define KDQ_PV    0.031496063f  /* 4/127 */

// ---------------- fp32 -> bf16 conversion (vectorized; bias) ----------------
__global__ __launch_bounds__(256) void cvt_bf16(const float4* __restrict__ in,
                                                ushort4* __restrict__ out) {
  size_t i = (size_t)blockIdx.x * 256 + threadIdx.x;
  float4 v = in[i];
  ushort4 o;
  o.x = f2bf(v.x); o.y = f2bf(v.y); o.z = f2bf(v.z); o.w = f2bf(v.w);
  out[i] = o;
}

// ------- x cvt: Xb bf16 [16384,1024], Xb8 i8 (scale QX), XT8 i8 transposed [1024,16384]
__global__ __launch_bounds__(256) void cvt_x_dual(const float* __restrict__ x,
                                                  unsigned short* __restrict__ Xb,
                                                  signed char* __restrict__ Xb8,
                                                  signed char* __restrict__ XT8) {
  __shared__ signed char tc[64][65];
  const int t0 = blockIdx.x * 64, i0 = blockIdx.y * 64;
  const int tx = threadIdx.x & 63, ty = threadIdx.x >> 6;
#pragma unroll
  for (int it = 0; it < 16; ++it) {
    int r = it * 4 + ty;
    float f = x[(size_t)(t0 + r) * 1024 + i0 + tx];
    Xb[(size_t)(t0 + r) * 1024 + i0 + tx] = f2bf(f);
    signed char c = q8(f, QX);
    Xb8[(size_t)(t0 + r) * 1024 + i0 + tx] = c;
    tc[r][tx] = c;
  }
  __syncthreads();
#pragma unroll
  for (int it = 0; it < 16; ++it) {
    int r = it * 4 + ty;
    XT8[(size_t)(i0 + r) * 16384 + t0 + tx] = tc[tx][r];
  }
}

// ------- z-batched weight cvt: z<3 transpose Wq/Wk/Wv; z=3 plain-convert Wout -------
__global__ __launch_bounds__(256) void cvt_w4(const float* __restrict__ Wqkv,
                                              const float* __restrict__ Wout,
                                              unsigned short* __restrict__ o0,
                                              unsigned short* __restrict__ o1,
                                              unsigned short* __restrict__ o2,
                                              unsigned short* __restrict__ o3) {
  __shared__ unsigned short tl[64][65];
  const int z = blockIdx.z;
  const int r0 = blockIdx.x * 64, c0 = blockIdx.y * 64;
  const int tx = threadIdx.x & 63, ty = threadIdx.x >> 6;
  if (z == 3) {
#pragma unroll
    for (int it = 0; it < 16; ++it) {
      int r = it * 4 + ty;
      o3[(size_t)(r0 + r) * 1024 + c0 + tx] = f2bf(Wout[(size_t)(r0 + r) * 1024 + c0 + tx]);
    }
    return;
  }
  const float* src = Wqkv + (size_t)z * 1024 * 1024;
  unsigned short* outT = z == 0 ? o0 : (z == 1 ? o1 : o2);
#pragma unroll
  for (int it = 0; it < 16; ++it) {
    int r = it * 4 + ty;
    tl[r][tx] = f2bf(src[(size_t)(r0 + r) * 1024 + c0 + tx]);
  }
  __syncthreads();
#pragma unroll
  for (int it = 0; it < 16; ++it) {
    int r = it * 4 + ty;
    outT[(size_t)(c0 + r) * 1024 + r0 + tx] = tl[tx][r];
  }
}

// ------- z-batched row-dot: z=0 bfv = Wout*bv + bout ; z=1 a2 = Wk^T bq / 32 -------
__global__ __launch_bounds__(256) void dotrows2(const unsigned short* __restrict__ W0,
                                                const float* __restrict__ v0,
                                                const float* __restrict__ add0,
                                                float* __restrict__ out0,
                                                const unsigned short* __restrict__ W1,
                                                const float* __restrict__ v1,
                                                float* __restrict__ out1) {
  const int z = blockIdx.y;
  const unsigned short* W = z ? W1 : W0;
  const float* vec = z ? v1 : v0;
  const float scale = z ? 0.03125f : 1.0f;
  const int o = blockIdx.x * 4 + (threadIdx.x >> 6);
  const int lane = threadIdx.x & 63;
  const short8 w0 = *(const short8*)&W[(size_t)o * 1024 + lane * 16];
  const short8 w1 = *(const short8*)&W[(size_t)o * 1024 + lane * 16 + 8];
  float s = 0.f;
#pragma unroll
  for (int j = 0; j < 8; ++j) s += bf2f((unsigned short)w0[j]) * vec[lane * 16 + j];
#pragma unroll
  for (int j = 0; j < 8; ++j) s += bf2f((unsigned short)w1[j]) * vec[lane * 16 + 8 + j];
#pragma unroll
  for (int off = 1; off < 64; off <<= 1) s += __shfl_xor(s, off);
  if (lane == 0) {
    if (z) out1[o] = s * scale;
    else   out0[o] = s + add0[o];
  }
}

// ------- w[row] = Xb[row,:].a2  (one wave per row, 4 rows/block) -------------------
__global__ __launch_bounds__(256) void wvec_k(const unsigned short* __restrict__ Xb,
                                              const float* __restrict__ a2,
                                              float* __restrict__ w) {
  const int row = blockIdx.x * 4 + (threadIdx.x >> 6);
  const int lane = threadIdx.x & 63;
  const short8 x0 = *(const short8*)&Xb[(size_t)row * 1024 + lane * 16];
  const short8 x1 = *(const short8*)&Xb[(size_t)row * 1024 + lane * 16 + 8];
  float s = 0.f;
#pragma unroll
  for (int j = 0; j < 8; ++j) s += bf2f((unsigned short)x0[j]) * a2[lane * 16 + j];
#pragma unroll
  for (int j = 0; j < 8; ++j) s += bf2f((unsigned short)x1[j]) * a2[lane * 16 + 8 + j];
#pragma unroll
  for (int off = 1; off < 64; off <<= 1) s += __shfl_xor(s, off);
  if (lane == 0) w[row] = s;
}

// ------- finish rowsums: R[z,row] = sum over 32 slabs of psum[z][slab][row] -------
__global__ __launch_bounds__(256) void finish_rowsum(const float* __restrict__ psum,
                                                     float* __restrict__ R) {
  const int z = blockIdx.y;
  const int row = blockIdx.x * 256 + threadIdx.x;
  const float* p = psum + (size_t)z * 32 * 2048 + row;
  float s = 0.f;
#pragma unroll
  for (int k = 0; k < 32; ++k) s += p[k * 2048];
  R[(size_t)z * 2048 + row] = s;
}

// ====== split-K 128x128 bf16 GEMM partials: z = prob + 2*slice (4 K-slices of 256) ===
__global__ __launch_bounds__(256) void gemm128sk(
    const unsigned short* __restrict__ A0, const unsigned short* __restrict__ B0,
    const unsigned short* __restrict__ A1, const unsigned short* __restrict__ B1,
    float* __restrict__ pw) {
  __shared__ __align__(16) unsigned short Al[128 * 32];
  __shared__ __align__(16) unsigned short Bl[128 * 32];
  const int prob = blockIdx.z & 1, slice = blockIdx.z >> 1;
  const unsigned short* A = prob ? A1 : A0;
  const unsigned short* Bmat = prob ? B1 : B0;
  float* C = pw + ((size_t)prob * 4 + slice) * 1048576;
  const int kbase = slice * 256;

  const int tid = threadIdx.x;
  const int wid = tid >> 6, lane = tid & 63;
  const int wm = wid >> 1, wn = wid & 1;
  const int tm = blockIdx.x * 128, tn = blockIdx.y * 128;
  const int l16 = lane & 15, lk = lane >> 4;

  f32x4 acc[4][4];
#pragma unroll
  for (int i = 0; i < 4; ++i)
#pragma unroll
    for (int j = 0; j < 4; ++j) acc[i][j] = (f32x4){0.f, 0.f, 0.f, 0.f};

  const int ks = (lk ^ ((l16 >> 1) & 3)) * 8;

  for (int k0 = kbase; k0 < kbase + 256; k0 += 32) {
    __syncthreads();
#pragma unroll
    for (int it = 0; it < 2; ++it) {
      int chunk = it * 256 + tid;
      int row = chunk >> 2;
      int q = chunk & 3;
      int qs = q ^ ((row >> 1) & 3);
      const char* g = (const char*)(A + (size_t)(tm + row) * 1024 + k0) + qs * 16;
      async16(g, ((char*)Al) + it * 4096 + wid * 1024);
    }
#pragma unroll
    for (int it = 0; it < 2; ++it) {
      int chunk = it * 256 + tid;
      int row = chunk >> 2;
      int q = chunk & 3;
      int qs = q ^ ((row >> 1) & 3);
      const char* g = (const char*)(Bmat + (size_t)(tn + row) * 1024 + k0) + qs * 16;
      async16(g, ((char*)Bl) + it * 4096 + wid * 1024);
    }
    __syncthreads();

    short8 a[4], b[4];
#pragma unroll
    for (int i = 0; i < 4; ++i)
      a[i] = *(const short8*)&Al[(wm * 64 + i * 16 + l16) * 32 + ks];
#pragma unroll
    for (int j = 0; j < 4; ++j)
      b[j] = *(const short8*)&Bl[(wn * 64 + j * 16 + l16) * 32 + ks];
#pragma unroll
    for (int i = 0; i < 4; ++i)
#pragma unroll
      for (int j = 0; j < 4; ++j)
        acc[i][j] = __builtin_amdgcn_mfma_f32_16x16x32_bf16(a[i], b[j], acc[i][j], 0, 0, 0);
  }

#pragma unroll
  for (int i = 0; i < 4; ++i)
#pragma unroll
    for (int j = 0; j < 4; ++j) {
      int col = tn + wn * 64 + j * 16 + l16;
      int rbase = tm + wm * 64 + i * 16 + lk * 4;
#pragma unroll
      for (int r = 0; r < 4; ++r)
        C[(size_t)(rbase + r) * 1024 + col] = acc[i][j][r];
    }
}

// ------- sum the 4 K-slices -> bf16 BH / Wf -------------------------------------
__global__ __launch_bounds__(256) void finish_w(const float* __restrict__ pw,
                                                unsigned short* __restrict__ BH,
                                                unsigned short* __restrict__ Wf) {
  const int prob = blockIdx.y;
  const size_t i = ((size_t)blockIdx.x * 256 + threadIdx.x) * 2;
  const float* p = pw + (size_t)prob * 4194304;
  float s0 = 0.f, s1 = 0.f;
#pragma unroll
  for (int k = 0; k < 4; ++k) {
    const float2 v = *(const float2*)(p + (size_t)k * 1048576 + i);
    s0 += v.x; s1 += v.y;
  }
  const float sc = prob ? 1.0f : 0.03125f;
  unsigned short* dst = prob ? Wf : BH;
  dst[i] = f2bf(s0 * sc);
  dst[i + 1] = f2bf(s1 * sc);
}

// ============ 256x256 bf16 GEMM, BK=32, 64KB LDS, 2 blocks/CU, 1 barrier/tile =======
// Catalog minimum-2-phase recipe: {STAGE(t+1)->buf^1 ; read frags buf ; MFMA ;
// vmcnt(0) ; s_barrier ; compiler-fence}.  Full A+B double-buffer -> stage never
// touches the buffer being read; each wave's reads drain (compiler lgkm at MFMA use)
// before it reaches the barrier, so one barrier per tile is race-free.
// Chunk swizzle (64B rows, 4 chunks): chunk' = chunk ^ (row&3), both-sides (rule #21).
// EPI: 1 +biasv[col] (fp32/bf16 out); 6 quantize to i8 with scale
template <int EPI, typename OutT>
__global__ __launch_bounds__(512, 2) void gemm8p(
    const unsigned short* __restrict__ A, int lda, long long strA,
    const unsigned short* __restrict__ Bm, int ldb, long long strB,
    OutT* __restrict__ C, int ldc, long long strC, int K,
    const float* __restrict__ biasv, float scale) {
  __shared__ __align__(16) char lds[65536];   // A: buf*16K ; B: 32K + buf*16K
  const int tid = threadIdx.x;
  const int wid = tid >> 6, lane = tid & 63;
  const int wm = wid >> 2, wn = wid & 3;
  const int l16 = lane & 15, lk = lane >> 4;
  const int zz = blockIdx.z;

  const int nx = gridDim.x;
  const int nwg = nx * gridDim.y;
  const int bid = blockIdx.y * nx + blockIdx.x;
  const int swz = (bid & 7) * (nwg >> 3) + (bid >> 3);
  const int tm = (swz % nx) * 256, tn = (swz / nx) * 256;

  A += (size_t)zz * strA;
  Bm += (size_t)zz * strB;
  C += (size_t)zz * strC;

  const int nt = K >> 5;  // BK=32 (callers: K=1024 -> 32 tiles, even)

  const int srow = lane >> 2;                 // staging: lane covers (row srow, chunk lane&3)
  const int sgq = (lane & 3) ^ (srow & 3);    // pre-swizzled source chunk
  const int qa = (lk ^ (l16 & 3)) << 4;       // swizzled read chunk byte offset

  f32x4 acc[8][4];
#pragma unroll
  for (int i = 0; i < 8; ++i)
#pragma unroll
    for (int j = 0; j < 4; ++j) acc[i][j] = (f32x4){0.f, 0.f, 0.f, 0.f};

#define STAGE(tt)                                                                      \
  {                                                                                    \
    const int buf_ = (tt) & 1, k0_ = (tt) << 5;                                        \
    _Pragma("unroll")                                                                  \
    for (int is = 0; is < 2; ++is) {                                                   \
      const unsigned short* gA_ =                                                      \
          A + (size_t)(tm + is * 128 + wid * 16 + srow) * lda + k0_ + sgq * 8;         \
      async16(gA_, lds + buf_ * 16384 + is * 8192 + wid * 1024);                       \
      const unsigned short* gB_ =                                                      \
          Bm + (size_t)(tn + is * 128 + wid * 16 + srow) * ldb + k0_ + sgq * 8;        \
      async16(gB_, lds + 32768 + buf_ * 16384 + is * 8192 + wid * 1024);               \
    }                                                                                  \
  }
#define TILE(tt, cur_)                                                                 \
  {                                                                                    \
    if ((tt) + 1 < nt) STAGE((tt) + 1);                                                \
    const char* aB = lds + (cur_) * 16384;                                             \
    const char* bB = lds + 32768 + (cur_) * 16384;                                     \
    short8 b0 = *(const short8*)(bB + (wn * 64 + l16) * 64 + qa);                      \
    short8 b1 = *(const short8*)(bB + (wn * 64 + 16 + l16) * 64 + qa);                 \
    short8 b2 = *(const short8*)(bB + (wn * 64 + 32 + l16) * 64 + qa);                 \
    short8 b3 = *(const short8*)(bB + (wn * 64 + 48 + l16) * 64 + qa);                 \
    __builtin_amdgcn_s_setprio(1);                                                     \
    _Pragma("unroll")                                                                  \
    for (int fr = 0; fr < 8; ++fr) {                                                   \
      short8 a_ = *(const short8*)(aB + (wm * 128 + fr * 16 + l16) * 64 + qa);         \
      acc[fr][0] = __builtin_amdgcn_mfma_f32_16x16x32_bf16(a_, b0, acc[fr][0], 0, 0, 0); \
      acc[fr][1] = __builtin_amdgcn_mfma_f32_16x16x32_bf16(a_, b1, acc[fr][1], 0, 0, 0); \
      acc[fr][2] = __builtin_amdgcn_mfma_f32_16x16x32_bf16(a_, b2, acc[fr][2], 0, 0, 0); \
      acc[fr][3] = __builtin_amdgcn_mfma_f32_16x16x32_bf16(a_, b3, acc[fr][3], 0, 0, 0); \
    }                                                                                  \
    __builtin_amdgcn_s_setprio(0);                                                     \
    if ((tt) + 1 < nt) {                                                               \
      asm volatile("s_waitcnt vmcnt(0)" ::: "memory");                                 \
      __builtin_amdgcn_s_barrier();                                                    \
      asm volatile("" ::: "memory");                                                   \
    }                                                                                  \
  }

  STAGE(0);
  asm volatile("s_waitcnt vmcnt(0)" ::: "memory");
  __builtin_amdgcn_s_barrier();
  asm volatile("" ::: "memory");

  for (int t = 0; t + 1 < nt; t += 2) { TILE(t, 0) TILE(t + 1, 1) }
#undef STAGE
#undef TILE

  // epilogue: D row=(lane>>4)*4+r, col=lane&15 per 16x16 frag (verified mapping)
#pragma unroll
  for (int fr = 0; fr < 8; ++fr) {
    const int rbase = tm + wm * 128 + fr * 16 + lk * 4;
#pragma unroll
    for (int wc = 0; wc < 4; ++wc) {
      const int col = tn + wn * 64 + wc * 16 + l16;
#pragma unroll
      for (int r = 0; r < 4; ++r) {
        float v = acc[fr][wc][r];
        const int row = rbase + r;
        if constexpr (EPI == 1) {
          v += biasv[col];
          storeC(&C[(size_t)row * ldc + col], v);
        } else if constexpr (EPI == 6) {
          C[(size_t)row * ldc + col] = (OutT)q8(v, scale);
        } else {
          storeC(&C[(size_t)row * ldc + col], v);
        }
      }
    }
  }
}

// ============ 256x256 INT8 GEMM, 16x16x64 i8, BK=64, 64KB LDS, 2 blocks/CU ==========
// Same skeleton/swizzle as gemm8p (64B rows).  EPI 4: P8 = round(exp(acc*kdq + bias
// + wv)*qp) + psum row partials (R = sum p8, P-scale cancels).  EPI 5: acc*kdq/R.
template <int EPI, typename OutT>
__global__ __launch_bounds__(512, 2) void gemm8i(
    const signed char* __restrict__ A, int lda, long long strA,
    const signed char* __restrict__ Bm, int ldb, long long strB,
    OutT* __restrict__ C, int ldc, long long strC, int K,
    const float* __restrict__ biasv,
    const unsigned short* __restrict__ biasm, int ldbm,
    float kdq, float qp, float* __restrict__ psum) {
  __shared__ __align__(16) char lds[65536];
  const int tid = threadIdx.x;
  const int wid = tid >> 6, lane = tid & 63;
  const int wm = wid >> 2, wn = wid & 3;
  const int l16 = lane & 15, lk = lane >> 4;
  const int zz = blockIdx.z;

  const int nx = gridDim.x;
  const int nwg = nx * gridDim.y;
  const int bid = blockIdx.y * nx + blockIdx.x;
  const int swz = (bid & 7) * (nwg >> 3) + (bid >> 3);
  const int tm = (swz % nx) * 256, tn = (swz / nx) * 256;

  A += (size_t)zz * strA;
  Bm += (size_t)zz * strB;
  C += (size_t)zz * strC;

  const int nt = K >> 6;  // BK=64 (logits 16, PV 32 tiles, even)

  const int srow = lane >> 2;
  const int sgq = (lane & 3) ^ (srow & 3);
  const int qa = (lk ^ (l16 & 3)) << 4;

  int4v acc[8][4];
#pragma unroll
  for (int i = 0; i < 8; ++i)
#pragma unroll
    for (int j = 0; j < 4; ++j) acc[i][j] = (int4v){0, 0, 0, 0};

#define STAGE(tt)                                                                      \
  {                                                                                    \
    const int buf_ = (tt) & 1, k0_ = (tt) << 6;                                        \
    _Pragma("unroll")                                                                  \
    for (int is = 0; is < 2; ++is) {                                                   \
      const signed char* gA_ =                                                         \
          A + (size_t)(tm + is * 128 + wid * 16 + srow) * lda + k0_ + sgq * 16;        \
      async16(gA_, lds + buf_ * 16384 + is * 8192 + wid * 1024);                       \
      const signed char* gB_ =                                                         \
          Bm + (size_t)(tn + is * 128 + wid * 16 + srow) * ldb + k0_ + sgq * 16;       \
      async16(gB_, lds + 32768 + buf_ * 16384 + is * 8192 + wid * 1024);               \
    }                                                                                  \
  }
#define TILE(tt, cur_)                                                                 \
  {                                                                                    \
    if ((tt) + 1 < nt) STAGE((tt) + 1);                                                \
    const char* aB = lds + (cur_) * 16384;                                             \
    const char* bB = lds + 32768 + (cur_) * 16384;                                     \
    int4v b0 = *(const int4v*)(bB + (wn * 64 + l16) * 64 + qa);                        \
    int4v b1 = *(const int4v*)(bB + (wn * 64 + 16 + l16) * 64 + qa);                   \
    int4v b2 = *(const int4v*)(bB + (wn * 64 + 32 + l16) * 64 + qa);                   \
    int4v b3 = *(const int4v*)(bB + (wn * 64 + 48 + l16) * 64 + qa);                   \
    __builtin_amdgcn_s_setprio(1);                                                     \
    _Pragma("unroll")                                                                  \
    for (int fr = 0; fr < 8; ++fr) {                                                   \
      int4v a_ = *(const int4v*)(aB + (wm * 128 + fr * 16 + l16) * 64 + qa);           \
      acc[fr][0] = __builtin_amdgcn_mfma_i32_16x16x64_i8(a_, b0, acc[fr][0], 0, 0, 0); \
      acc[fr][1] = __builtin_amdgcn_mfma_i32_16x16x64_i8(a_, b1, acc[fr][1], 0, 0, 0); \
      acc[fr][2] = __builtin_amdgcn_mfma_i32_16x16x64_i8(a_, b2, acc[fr][2], 0, 0, 0); \
      acc[fr][3] = __builtin_amdgcn_mfma_i32_16x16x64_i8(a_, b3, acc[fr][3], 0, 0, 0); \
    }                                                                                  \
    __builtin_amdgcn_s_setprio(0);                                                     \
    if ((tt) + 1 < nt) {                                                               \
      asm volatile("s_waitcnt vmcnt(0)" ::: "memory");                                 \
      __builtin_amdgcn_s_barrier();                                                    \
      asm volatile("" ::: "memory");                                                   \
    }                                                                                  \
  }

  STAGE(0);
  asm volatile("s_waitcnt vmcnt(0)" ::: "memory");
  __builtin_amdgcn_s_barrier();
  asm volatile("" ::: "memory");

  for (int t = 0; t + 1 < nt; t += 2) { TILE(t, 0) TILE(t + 1, 1) }
#undef STAGE
#undef TILE

  // epilogue: C/D mapping dtype-independent: row=(lane>>4)*4+r, col=lane&15
#pragma unroll
  for (int fr = 0; fr < 8; ++fr) {
    const int rbase = tm + wm * 128 + fr * 16 + lk * 4;
    float rin[4];
    if constexpr (EPI == 5) {
#pragma unroll
      for (int r = 0; r < 4; ++r)
        rin[r] = kdq / biasv[(size_t)zz * ldbm + rbase + r];
    }
    float rs[4] = {0.f, 0.f, 0.f, 0.f};
#pragma unroll
    for (int wc = 0; wc < 4; ++wc) {
      const int col = tn + wn * 64 + wc * 16 + l16;
#pragma unroll
      for (int r = 0; r < 4; ++r) {
        const int row = rbase + r;
        if constexpr (EPI == 4) {
          float v = (float)acc[fr][wc][r] * kdq;
          v = __expf(v + bf2f(biasm[(size_t)row * ldbm + col]) +
                     biasv[(size_t)zz * T_DIM + col]);
          int q = (int)(v * qp + 0.5f);
          q = q > 127 ? 127 : q;
          C[(size_t)row * ldc + col] = (OutT)(signed char)q;
          rs[r] += (float)q;
        } else if constexpr (EPI == 5) {
          float v = (float)acc[fr][wc][r] * rin[r];
          storeC(&C[(size_t)row * ldc + col], v);
        }
      }
    }
    if constexpr (EPI == 4) {
#pragma unroll
      for (int r = 0; r < 4; ++r) {
#pragma unroll
        for (int off = 1; off < 16; off <<= 1) rs[r] += __shfl_xor(rs[r], off);
      }
      if (l16 == 0) {
        const int slab = ((zz * 8 + (tn >> 8)) * 4 + wn);
#pragma unroll
        for (int r = 0; r < 4; ++r)
          psum[(size_t)slab * 2048 + rbase + r] = rs[r];
      }
    }
  }
}

// ---------------- launch ----------------
extern "C" void kernel_launch(void* const* d_in, const int* in_sizes, int n_in,
                              void* d_out, int out_size, void* d_ws, size_t ws_size,
                              hipStream_t stream) {
  const float* x = (const float*)d_in[0];     // [8,2048,1024]
  const float* bias = (const float*)d_in[1];  // [2048,2048] fp32
  const float* Wqkv = (const float*)d_in[2];  // [3072,1024]  (Wq|Wk|Wv)
  const float* bqkv = (const float*)d_in[3];  // [3072]       (bq|bk|bv)
  const float* Wout = (const float*)d_in[4];  // [1024,1024]
  const float* bout = (const float*)d_in[5];  // [1024]
  float* out = (float*)d_out;                 // [8,2048,1024] fp32

  char* ws = (char*)d_ws;
  unsigned short* Xb    = (unsigned short*)(ws + 0);          // 33.5MB; reused as Valb
  signed char*    Xb8   = (signed char*)(ws + 33554432);      // 16.8MB i8 [16384,1024]
  signed char*    XT8   = (signed char*)(ws + 50331648);      // 16.8MB i8 [1024,16384]
  unsigned short* WqT   = (unsigned short*)(ws + 67108864);   // 2.1MB
  unsigned short* WkT   = (unsigned short*)(ws + 69206016);   // 2.1MB
  unsigned short* WvT   = (unsigned short*)(ws + 71303168);   // 2.1MB
  unsigned short* Woutb = (unsigned short*)(ws + 73400320);   // 2.1MB
  unsigned short* BH    = (unsigned short*)(ws + 75497472);   // 2.1MB (Wk^T Wq/32)^T
  unsigned short* Wfb   = (unsigned short*)(ws + 77594624);   // 2.1MB Wout*Wv
  float*          bfv   = (float*)(ws + 79691776);            // 4KB
  float*          a2    = (float*)(ws + 79695872);            // 4KB
  float*          wv    = (float*)(ws + 79699968);            // 64KB [8,2048]
  signed char*    Y8    = (signed char*)(ws + 79765504);      // 16.8MB i8 [16384,1024]
  unsigned short* biasb = (unsigned short*)(ws + 96542720);   // 8.4MB bf16
  signed char*    P8    = (signed char*)(ws + 104931328);     // 33.5MB i8 [8,2048,2048]
  float*          pw    = (float*)(ws + 104931328);           // 33.5MB splitK partials (pre-P8)
  float*          psum  = (float*)(ws + 138485760);           // 2MB [8][32][2048]
  unsigned short* Valb  = Xb;                                 // overlays Xb (dead after Y-GEMM)
  float*          R     = out + ((size_t)out_size - B_DIM * T_DIM);  // out tail scratch

  const long long sX8  = (long long)T_DIM * 1024;   // i8 per-batch stride (Y8/Xb8)
  const long long sTT8 = (long long)T_DIM * T_DIM;  // P8 batch stride
  const long long sTE  = (long long)T_DIM * E_DIM;

  // 1) conversions (x -> bf16 + i8 + i8-transposed; weights incl. Wout; bias)
  cvt_x_dual<<<dim3(256, 16), 256, 0, stream>>>(x, Xb, Xb8, XT8);
  cvt_w4<<<dim3(16, 16, 4), 256, 0, stream>>>(Wqkv, Wout, WqT, WkT, WvT, Woutb);
  cvt_bf16<<<4096, 256, 0, stream>>>((const float4*)bias, (ushort4*)biasb);

  // 2) small fused constants
  dotrows2<<<dim3(256, 2), 256, 0, stream>>>(Woutb, bqkv + 2048, bout, bfv,
                                             WkT, bqkv, a2);
  gemm128sk<<<dim3(8, 8, 8), 256, 0, stream>>>(WkT, WqT, Woutb, WvT, pw);
  finish_w<<<dim3(2048, 2), 256, 0, stream>>>(pw, BH, Wfb);
  wvec_k<<<4096, 256, 0, stream>>>(Xb, a2, wv);

  // 3) Y = X*H (bf16 in, i8 out at scale QY)
  gemm8p<6, signed char><<<dim3(64, 4, 1), 512, 0, stream>>>(
      Xb, 1024, 0, BH, 1024, 0, Y8, 1024, 0, 1024, nullptr, QY);

  // 4) logits (i8 x i8 -> i32): P8 = round(exp(acc*kdq + bias + wv)*QP), + psum
  gemm8i<4, signed char><<<dim3(8, 8, B_DIM), 512, 0, stream>>>(
      Y8, 1024, sX8, Xb8, 1024, sX8, P8, T_DIM, sTT8, 1024,
      wv, biasb, T_DIM, KDQ_LOGIT, QP, psum);

  // 5) R[z,t] = sum_s P8  (P-scale cancels in the normalization)
  finish_rowsum<<<dim3(8, B_DIM), 256, 0, stream>>>(psum, R);

  // 6) PV (i8 x i8): Val = (sum_s P8*X8) * (4/127) / R   (bf16 out)
  gemm8i<5, unsigned short><<<dim3(8, 4, B_DIM), 512, 0, stream>>>(
      P8, T_DIM, sTT8, XT8, 8 * T_DIM, T_DIM,
      Valb, E_DIM, sTE, T_DIM, R, nullptr, T_DIM, KDQ_PV, 0.f, nullptr);

  // 7) fused output projection: out = Val*Wf^T + bfv
  gemm8p<1, float><<<dim3(64, 4, 1), 512, 0, stream>>>(
      Valb, 1024, 0, Wfb, 1024, 0, out, 1024, 0, 1024, bfv, 0.f);
}

// Round 15
// 232.858 us; speedup vs baseline: 1.1420x; 1.1420x over previous
//
#include <hip/hip_runtime.h>
#include <hip/hip_bf16.h>

// Problem: B=8, T=2048, D_IN=D_EMB=D_OUT=1024
#define B_DIM 8
#define T_DIM 2048
#define E_DIM 1024

typedef __attribute__((ext_vector_type(8))) short short8;
typedef __attribute__((ext_vector_type(4))) float f32x4;
typedef __attribute__((ext_vector_type(4))) int int4v;

__device__ __forceinline__ unsigned short f2bf(float f) {
  union { float f; unsigned u; } v; v.f = f;
  unsigned r = v.u + 0x7fffu + ((v.u >> 16) & 1u);
  return (unsigned short)(r >> 16);
}
__device__ __forceinline__ float bf2f(unsigned short u) {
  union { unsigned u; float f; } v; v.u = ((unsigned)u) << 16;
  return v.f;
}
__device__ __forceinline__ signed char q8(float f, float scale) {
  int q = __float2int_rn(f * scale);
  q = q > 127 ? 127 : (q < -127 ? -127 : q);
  return (signed char)q;
}

__device__ __forceinline__ void async16(const void* g, void* l) {
  __builtin_amdgcn_global_load_lds(
      (const __attribute__((address_space(1))) unsigned int*)g,
      (__attribute__((address_space(3))) unsigned int*)l, 16, 0, 0);
}

__device__ __forceinline__ void storeC(float* p, float v) { *p = v; }
__device__ __forceinline__ void storeC(unsigned short* p, float v) { *p = f2bf(v); }
__device__ __forceinline__ void storeC(signed char* p, float v) { *p = (signed char)(int)v; }

// quantization constants
#define QX 31.75f               /* x:  127/4    */
#define QY 1814.2857f           /* Y:  127/0.07 */
#define QP 15.875f              /* P:  127/8    */
#define KDQ_LOGIT 1.7359973e-5f /* (0.07/127)*(4/127) */
#define KDQ_PV    0.031496063f  /* 4/127 */

// ---------------- fp32 -> bf16 conversion (vectorized) ----------------
__global__ __launch_bounds__(256) void cvt_bf16(const float4* __restrict__ in,
                                                ushort4* __restrict__ out) {
  size_t i = (size_t)blockIdx.x * 256 + threadIdx.x;
  float4 v = in[i];
  ushort4 o;
  o.x = f2bf(v.x); o.y = f2bf(v.y); o.z = f2bf(v.z); o.w = f2bf(v.w);
  out[i] = o;
}

// ------- x cvt: Xb bf16 [16384,1024], Xb8 i8 (scale QX), XT8 i8 transposed [1024,16384]
__global__ __launch_bounds__(256) void cvt_x_dual(const float* __restrict__ x,
                                                  unsigned short* __restrict__ Xb,
                                                  signed char* __restrict__ Xb8,
                                                  signed char* __restrict__ XT8) {
  __shared__ signed char tc[64][65];
  const int t0 = blockIdx.x * 64, i0 = blockIdx.y * 64;
  const int tx = threadIdx.x & 63, ty = threadIdx.x >> 6;
#pragma unroll
  for (int it = 0; it < 16; ++it) {
    int r = it * 4 + ty;
    float f = x[(size_t)(t0 + r) * 1024 + i0 + tx];
    Xb[(size_t)(t0 + r) * 1024 + i0 + tx] = f2bf(f);
    signed char c = q8(f, QX);
    Xb8[(size_t)(t0 + r) * 1024 + i0 + tx] = c;
    tc[r][tx] = c;
  }
  __syncthreads();
#pragma unroll
  for (int it = 0; it < 16; ++it) {
    int r = it * 4 + ty;
    XT8[(size_t)(i0 + r) * 16384 + t0 + tx] = tc[tx][r];
  }
}

// ------- z-batched weight cvt: z<3 transpose Wq/Wk/Wv; z=3 plain-convert Wout -------
__global__ __launch_bounds__(256) void cvt_w4(const float* __restrict__ Wqkv,
                                              const float* __restrict__ Wout,
                                              unsigned short* __restrict__ o0,
                                              unsigned short* __restrict__ o1,
                                              unsigned short* __restrict__ o2,
                                              unsigned short* __restrict__ o3) {
  __shared__ unsigned short tl[64][65];
  const int z = blockIdx.z;
  const int r0 = blockIdx.x * 64, c0 = blockIdx.y * 64;
  const int tx = threadIdx.x & 63, ty = threadIdx.x >> 6;
  if (z == 3) {
#pragma unroll
    for (int it = 0; it < 16; ++it) {
      int r = it * 4 + ty;
      o3[(size_t)(r0 + r) * 1024 + c0 + tx] = f2bf(Wout[(size_t)(r0 + r) * 1024 + c0 + tx]);
    }
    return;
  }
  const float* src = Wqkv + (size_t)z * 1024 * 1024;
  unsigned short* outT = z == 0 ? o0 : (z == 1 ? o1 : o2);
#pragma unroll
  for (int it = 0; it < 16; ++it) {
    int r = it * 4 + ty;
    tl[r][tx] = f2bf(src[(size_t)(r0 + r) * 1024 + c0 + tx]);
  }
  __syncthreads();
#pragma unroll
  for (int it = 0; it < 16; ++it) {
    int r = it * 4 + ty;
    outT[(size_t)(c0 + r) * 1024 + r0 + tx] = tl[tx][r];
  }
}

// ------- z-batched row-dot: z=0 bfv = Wout*bv + bout ; z=1 a2 = Wk^T bq / 32 -------
__global__ __launch_bounds__(256) void dotrows2(const unsigned short* __restrict__ W0,
                                                const float* __restrict__ v0,
                                                const float* __restrict__ add0,
                                                float* __restrict__ out0,
                                                const unsigned short* __restrict__ W1,
                                                const float* __restrict__ v1,
                                                float* __restrict__ out1) {
  const int z = blockIdx.y;
  const unsigned short* W = z ? W1 : W0;
  const float* vec = z ? v1 : v0;
  const float scale = z ? 0.03125f : 1.0f;
  const int o = blockIdx.x * 4 + (threadIdx.x >> 6);
  const int lane = threadIdx.x & 63;
  const short8 w0 = *(const short8*)&W[(size_t)o * 1024 + lane * 16];
  const short8 w1 = *(const short8*)&W[(size_t)o * 1024 + lane * 16 + 8];
  float s = 0.f;
#pragma unroll
  for (int j = 0; j < 8; ++j) s += bf2f((unsigned short)w0[j]) * vec[lane * 16 + j];
#pragma unroll
  for (int j = 0; j < 8; ++j) s += bf2f((unsigned short)w1[j]) * vec[lane * 16 + 8 + j];
#pragma unroll
  for (int off = 1; off < 64; off <<= 1) s += __shfl_xor(s, off);
  if (lane == 0) {
    if (z) out1[o] = s * scale;
    else   out0[o] = s + add0[o];
  }
}

// ------- w[row] = Xb[row,:].a2  (one wave per row, 4 rows/block) -------------------
__global__ __launch_bounds__(256) void wvec_k(const unsigned short* __restrict__ Xb,
                                              const float* __restrict__ a2,
                                              float* __restrict__ w) {
  const int row = blockIdx.x * 4 + (threadIdx.x >> 6);
  const int lane = threadIdx.x & 63;
  const short8 x0 = *(const short8*)&Xb[(size_t)row * 1024 + lane * 16];
  const short8 x1 = *(const short8*)&Xb[(size_t)row * 1024 + lane * 16 + 8];
  float s = 0.f;
#pragma unroll
  for (int j = 0; j < 8; ++j) s += bf2f((unsigned short)x0[j]) * a2[lane * 16 + j];
#pragma unroll
  for (int j = 0; j < 8; ++j) s += bf2f((unsigned short)x1[j]) * a2[lane * 16 + 8 + j];
#pragma unroll
  for (int off = 1; off < 64; off <<= 1) s += __shfl_xor(s, off);
  if (lane == 0) w[row] = s;
}

// ------- finish rowsums: R[z,row] = sum over 32 slabs of psum[z][slab][row] -------
__global__ __launch_bounds__(256) void finish_rowsum(const float* __restrict__ psum,
                                                     float* __restrict__ R) {
  const int z = blockIdx.y;
  const int row = blockIdx.x * 256 + threadIdx.x;
  const float* p = psum + (size_t)z * 32 * 2048 + row;
  float s = 0.f;
#pragma unroll
  for (int k = 0; k < 32; ++k) s += p[k * 2048];
  R[(size_t)z * 2048 + row] = s;
}

// ====== split-K 128x128 bf16 GEMM partials: z = prob + 2*slice (4 K-slices of 256) ===
__global__ __launch_bounds__(256) void gemm128sk(
    const unsigned short* __restrict__ A0, const unsigned short* __restrict__ B0,
    const unsigned short* __restrict__ A1, const unsigned short* __restrict__ B1,
    float* __restrict__ pw) {
  __shared__ __align__(16) unsigned short Al[128 * 32];
  __shared__ __align__(16) unsigned short Bl[128 * 32];
  const int prob = blockIdx.z & 1, slice = blockIdx.z >> 1;
  const unsigned short* A = prob ? A1 : A0;
  const unsigned short* Bmat = prob ? B1 : B0;
  float* C = pw + ((size_t)prob * 4 + slice) * 1048576;
  const int kbase = slice * 256;

  const int tid = threadIdx.x;
  const int wid = tid >> 6, lane = tid & 63;
  const int wm = wid >> 1, wn = wid & 1;
  const int tm = blockIdx.x * 128, tn = blockIdx.y * 128;
  const int l16 = lane & 15, lk = lane >> 4;

  f32x4 acc[4][4];
#pragma unroll
  for (int i = 0; i < 4; ++i)
#pragma unroll
    for (int j = 0; j < 4; ++j) acc[i][j] = (f32x4){0.f, 0.f, 0.f, 0.f};

  const int ks = (lk ^ ((l16 >> 1) & 3)) * 8;

  for (int k0 = kbase; k0 < kbase + 256; k0 += 32) {
    __syncthreads();
#pragma unroll
    for (int it = 0; it < 2; ++it) {
      int chunk = it * 256 + tid;
      int row = chunk >> 2;
      int q = chunk & 3;
      int qs = q ^ ((row >> 1) & 3);
      const char* g = (const char*)(A + (size_t)(tm + row) * 1024 + k0) + qs * 16;
      async16(g, ((char*)Al) + it * 4096 + wid * 1024);
    }
#pragma unroll
    for (int it = 0; it < 2; ++it) {
      int chunk = it * 256 + tid;
      int row = chunk >> 2;
      int q = chunk & 3;
      int qs = q ^ ((row >> 1) & 3);
      const char* g = (const char*)(Bmat + (size_t)(tn + row) * 1024 + k0) + qs * 16;
      async16(g, ((char*)Bl) + it * 4096 + wid * 1024);
    }
    __syncthreads();

    short8 a[4], b[4];
#pragma unroll
    for (int i = 0; i < 4; ++i)
      a[i] = *(const short8*)&Al[(wm * 64 + i * 16 + l16) * 32 + ks];
#pragma unroll
    for (int j = 0; j < 4; ++j)
      b[j] = *(const short8*)&Bl[(wn * 64 + j * 16 + l16) * 32 + ks];
#pragma unroll
    for (int i = 0; i < 4; ++i)
#pragma unroll
      for (int j = 0; j < 4; ++j)
        acc[i][j] = __builtin_amdgcn_mfma_f32_16x16x32_bf16(a[i], b[j], acc[i][j], 0, 0, 0);
  }

#pragma unroll
  for (int i = 0; i < 4; ++i)
#pragma unroll
    for (int j = 0; j < 4; ++j) {
      int col = tn + wn * 64 + j * 16 + l16;
      int rbase = tm + wm * 64 + i * 16 + lk * 4;
#pragma unroll
      for (int r = 0; r < 4; ++r)
        C[(size_t)(rbase + r) * 1024 + col] = acc[i][j][r];
    }
}

// ------- sum the 4 K-slices -> bf16 BH / Wf -------------------------------------
__global__ __launch_bounds__(256) void finish_w(const float* __restrict__ pw,
                                                unsigned short* __restrict__ BH,
                                                unsigned short* __restrict__ Wf) {
  const int prob = blockIdx.y;
  const size_t i = ((size_t)blockIdx.x * 256 + threadIdx.x) * 2;
  const float* p = pw + (size_t)prob * 4194304;
  float s0 = 0.f, s1 = 0.f;
#pragma unroll
  for (int k = 0; k < 4; ++k) {
    const float2 v = *(const float2*)(p + (size_t)k * 1048576 + i);
    s0 += v.x; s1 += v.y;
  }
  const float sc = prob ? 1.0f : 0.03125f;
  unsigned short* dst = prob ? Wf : BH;
  dst[i] = f2bf(s0 * sc);
  dst[i + 1] = f2bf(s1 * sc);
}

// ============ 256x256 bf16 GEMM, 16x16x32 core, 2 barriers per K-tile (R11/R12) =====
// 512 threads = 8 waves (2M x 4N), BK=64, 128KB LDS, chunk swizzle q' = q ^ (row&7)
// on BOTH stage-source and ds_read (rule #21).  Per K-tile: p0 {counted vmcnt ;
// s_barrier ; fence ; B reads + A rows0,1 ; STAGE_A(t+1,0) ; MFMA} ; p1 ; p2
// {s_barrier ; fence ; ...} ; p3.  Conflict-free (measured 0 @128B rows).
// EPI: 1 +biasv[col] (fp32/bf16 out); 6 quantize to i8 with scale
template <int EPI, typename OutT>
__global__ __launch_bounds__(512, 2) void gemm8p(
    const unsigned short* __restrict__ A, int lda, long long strA,
    const unsigned short* __restrict__ Bm, int ldb, long long strB,
    OutT* __restrict__ C, int ldc, long long strC, int K,
    const float* __restrict__ biasv, float scale) {
  __shared__ __align__(16) char lds[131072];
  const int tid = threadIdx.x;
  const int wid = tid >> 6, lane = tid & 63;
  const int wm = wid >> 2, wn = wid & 3;
  const int l16 = lane & 15, lk = lane >> 4;
  const int zz = blockIdx.z;

  const int nx = gridDim.x;
  const int nwg = nx * gridDim.y;
  const int bid = blockIdx.y * nx + blockIdx.x;
  const int swz = (bid & 7) * (nwg >> 3) + (bid >> 3);
  const int tm = (swz % nx) * 256, tn = (swz / nx) * 256;

  A += (size_t)zz * strA;
  Bm += (size_t)zz * strB;
  C += (size_t)zz * strC;

  const int nt = K >> 6;

  const int q0 = ((lk ^ (l16 & 7)) << 4);
  const int q1 = (((lk | 4) ^ (l16 & 7)) << 4);
  const int srow = lane >> 3;
  const int scol = ((lane & 7) ^ srow) << 3;

  f32x4 acc[8][4];
#pragma unroll
  for (int i = 0; i < 8; ++i)
#pragma unroll
    for (int j = 0; j < 4; ++j) acc[i][j] = (f32x4){0.f, 0.f, 0.f, 0.f};

  short8 bF[4][2];

#define STAGE_A(tt, h)                                                              \
  {                                                                                 \
    const int buf_ = (tt) & 1, k0_ = (tt) << 6;                                     \
    { const unsigned short* g_ =                                                    \
          A + (size_t)(tm + (h) * 128 + wid * 16 + srow) * lda + k0_ + scol;        \
      async16(g_, lds + (buf_ * 2 + (h)) * 16384 + wid * 2048); }                   \
    { const unsigned short* g_ =                                                    \
          A + (size_t)(tm + (h) * 128 + wid * 16 + 8 + srow) * lda + k0_ + scol;    \
      async16(g_, lds + (buf_ * 2 + (h)) * 16384 + wid * 2048 + 1024); }            \
  }
#define STAGE_B(tt, h)                                                              \
  {                                                                                 \
    const int buf_ = (tt) & 1, k0_ = (tt) << 6;                                     \
    { const unsigned short* g_ =                                                    \
          Bm + (size_t)(tn + (h) * 128 + wid * 16 + srow) * ldb + k0_ + scol;       \
      async16(g_, lds + 65536 + (buf_ * 2 + (h)) * 16384 + wid * 2048); }           \
    { const unsigned short* g_ =                                                    \
          Bm + (size_t)(tn + (h) * 128 + wid * 16 + 8 + srow) * ldb + k0_ + scol;   \
      async16(g_, lds + 65536 + (buf_ * 2 + (h)) * 16384 + wid * 2048 + 1024); }    \
  }
#define PHASE(tt, cur_, p_)                                                         \
  {                                                                                 \
    if ((p_) == 0) {                                                                \
      if ((tt) + 1 < nt) asm volatile("s_waitcnt vmcnt(4)" ::: "memory");           \
      else               asm volatile("s_waitcnt vmcnt(0)" ::: "memory");           \
      __builtin_amdgcn_s_barrier();                                                 \
      asm volatile("" ::: "memory");                                                \
    }                                                                               \
    if ((p_) == 2) {                                                                \
      __builtin_amdgcn_s_barrier();                                                 \
      asm volatile("" ::: "memory");                                                \
    }                                                                               \
    const char* aB = lds + ((cur_) * 2 + wm) * 16384 + l16 * 128;                   \
    const char* bB = lds + 65536 + ((cur_) * 2 + (wn >> 1)) * 16384 +               \
                     ((wn & 1) * 64 + l16) * 128;                                   \
    short8 a00 = *(const short8*)(aB + (2 * (p_)) * 2048 + q0);                     \
    short8 a01 = *(const short8*)(aB + (2 * (p_)) * 2048 + q1);                     \
    short8 a10 = *(const short8*)(aB + (2 * (p_) + 1) * 2048 + q0);                 \
    short8 a11 = *(const short8*)(aB + (2 * (p_) + 1) * 2048 + q1);                 \
    if ((p_) == 0) {                                                                \
      _Pragma("unroll")                                                             \
      for (int wc = 0; wc < 4; ++wc) {                                              \
        bF[wc][0] = *(const short8*)(bB + wc * 2048 + q0);                          \
        bF[wc][1] = *(const short8*)(bB + wc * 2048 + q1);                          \
      }                                                                             \
    }                                                                               \
    if ((p_) == 0 && (tt) + 1 < nt) STAGE_A((tt) + 1, 0);                           \
    if ((p_) == 1 && (tt) + 1 < nt) STAGE_A((tt) + 1, 1);                           \
    if ((p_) == 2 && (tt) + 2 < nt) STAGE_B((tt) + 2, 0);                           \
    if ((p_) == 3 && (tt) + 2 < nt) STAGE_B((tt) + 2, 1);                           \
    __builtin_amdgcn_s_setprio(1);                                                  \
    _Pragma("unroll")                                                               \
    for (int wc = 0; wc < 4; ++wc) {                                                \
      acc[2 * (p_)][wc] =                                                           \
          __builtin_amdgcn_mfma_f32_16x16x32_bf16(a00, bF[wc][0], acc[2 * (p_)][wc], 0, 0, 0); \
      acc[2 * (p_)][wc] =                                                           \
          __builtin_amdgcn_mfma_f32_16x16x32_bf16(a01, bF[wc][1], acc[2 * (p_)][wc], 0, 0, 0); \
      acc[2 * (p_) + 1][wc] =                                                       \
          __builtin_amdgcn_mfma_f32_16x16x32_bf16(a10, bF[wc][0], acc[2 * (p_) + 1][wc], 0, 0, 0); \
      acc[2 * (p_) + 1][wc] =                                                       \
          __builtin_amdgcn_mfma_f32_16x16x32_bf16(a11, bF[wc][1], acc[2 * (p_) + 1][wc], 0, 0, 0); \
    }                                                                               \
    __builtin_amdgcn_s_setprio(0);                                                  \
  }

  STAGE_A(0, 0); STAGE_A(0, 1); STAGE_B(0, 0); STAGE_B(0, 1);
  STAGE_B(1, 0); STAGE_B(1, 1);

  int t = 0;
  for (; t + 1 < nt; t += 2) {
    PHASE(t, 0, 0) PHASE(t, 0, 1) PHASE(t, 0, 2) PHASE(t, 0, 3)
    PHASE(t + 1, 1, 0) PHASE(t + 1, 1, 1) PHASE(t + 1, 1, 2) PHASE(t + 1, 1, 3)
  }
  if (t < nt) {
    const int c = t & 1;
    if (c == 0) { PHASE(t, 0, 0) PHASE(t, 0, 1) PHASE(t, 0, 2) PHASE(t, 0, 3) }
    else        { PHASE(t, 1, 0) PHASE(t, 1, 1) PHASE(t, 1, 2) PHASE(t, 1, 3) }
  }
#undef STAGE_A
#undef STAGE_B
#undef PHASE

#pragma unroll
  for (int fr = 0; fr < 8; ++fr) {
    const int rbase = tm + wm * 128 + fr * 16 + lk * 4;
#pragma unroll
    for (int wc = 0; wc < 4; ++wc) {
      const int col = tn + wn * 64 + wc * 16 + l16;
#pragma unroll
      for (int r = 0; r < 4; ++r) {
        float v = acc[fr][wc][r];
        const int row = rbase + r;
        if constexpr (EPI == 1) {
          v += biasv[col];
          storeC(&C[(size_t)row * ldc + col], v);
        } else if constexpr (EPI == 6) {
          C[(size_t)row * ldc + col] = (OutT)q8(v, scale);
        } else {
          storeC(&C[(size_t)row * ldc + col], v);
        }
      }
    }
  }
}

// ============ 256x256 INT8 GEMM, 16x16x64 i8 core, BK=128, 2 barriers/K-tile ========
// Same byte geometry as the bf16 core (128B LDS rows, identical swizzle/staging).
// EPI 4: P8 = round(exp(acc*kdq + bias + wv)*qp) (i8 out) + psum row partials
//        (R = sum p8, P-scale cancels).  EPI 5: v = acc*kdq/R (bf16 out).
template <int EPI, typename OutT>
__global__ __launch_bounds__(512, 2) void gemm8i(
    const signed char* __restrict__ A, int lda, long long strA,
    const signed char* __restrict__ Bm, int ldb, long long strB,
    OutT* __restrict__ C, int ldc, long long strC, int K,
    const float* __restrict__ biasv,
    const unsigned short* __restrict__ biasm, int ldbm,
    float kdq, float qp, float* __restrict__ psum) {
  __shared__ __align__(16) char lds[131072];
  const int tid = threadIdx.x;
  const int wid = tid >> 6, lane = tid & 63;
  const int wm = wid >> 2, wn = wid & 3;
  const int l16 = lane & 15, lk = lane >> 4;
  const int zz = blockIdx.z;

  const int nx = gridDim.x;
  const int nwg = nx * gridDim.y;
  const int bid = blockIdx.y * nx + blockIdx.x;
  const int swz = (bid & 7) * (nwg >> 3) + (bid >> 3);
  const int tm = (swz % nx) * 256, tn = (swz / nx) * 256;

  A += (size_t)zz * strA;
  Bm += (size_t)zz * strB;
  C += (size_t)zz * strC;

  const int nt = K >> 7;  // K-tiles of 128

  const int q0 = ((lk ^ (l16 & 7)) << 4);
  const int q1 = (((lk | 4) ^ (l16 & 7)) << 4);
  const int srow = lane >> 3;
  const int scol = ((lane & 7) ^ srow) << 4;  // i8: 16 elements per 16B chunk

  int4v acc[8][4];
#pragma unroll
  for (int i = 0; i < 8; ++i)
#pragma unroll
    for (int j = 0; j < 4; ++j) acc[i][j] = (int4v){0, 0, 0, 0};

  int4v bF[4][2];

#define STAGE_A(tt, h)                                                              \
  {                                                                                 \
    const int buf_ = (tt) & 1, k0_ = (tt) << 7;                                     \
    { const signed char* g_ =                                                       \
          A + (size_t)(tm + (h) * 128 + wid * 16 + srow) * lda + k0_ + scol;        \
      async16(g_, lds + (buf_ * 2 + (h)) * 16384 + wid * 2048); }                   \
    { const signed char* g_ =                                                       \
          A + (size_t)(tm + (h) * 128 + wid * 16 + 8 + srow) * lda + k0_ + scol;    \
      async16(g_, lds + (buf_ * 2 + (h)) * 16384 + wid * 2048 + 1024); }            \
  }
#define STAGE_B(tt, h)                                                              \
  {                                                                                 \
    const int buf_ = (tt) & 1, k0_ = (tt) << 7;                                     \
    { const signed char* g_ =                                                       \
          Bm + (size_t)(tn + (h) * 128 + wid * 16 + srow) * ldb + k0_ + scol;       \
      async16(g_, lds + 65536 + (buf_ * 2 + (h)) * 16384 + wid * 2048); }           \
    { const signed char* g_ =                                                       \
          Bm + (size_t)(tn + (h) * 128 + wid * 16 + 8 + srow) * ldb + k0_ + scol;   \
      async16(g_, lds + 65536 + (buf_ * 2 + (h)) * 16384 + wid * 2048 + 1024); }    \
  }
#define PHASE(tt, cur_, p_)                                                         \
  {                                                                                 \
    if ((p_) == 0) {                                                                \
      if ((tt) + 1 < nt) asm volatile("s_waitcnt vmcnt(4)" ::: "memory");           \
      else               asm volatile("s_waitcnt vmcnt(0)" ::: "memory");           \
      __builtin_amdgcn_s_barrier();                                                 \
      asm volatile("" ::: "memory");                                                \
    }                                                                               \
    if ((p_) == 2) {                                                                \
      __builtin_amdgcn_s_barrier();                                                 \
      asm volatile("" ::: "memory");                                                \
    }                                                                               \
    const char* aB = lds + ((cur_) * 2 + wm) * 16384 + l16 * 128;                   \
    const char* bB = lds + 65536 + ((cur_) * 2 + (wn >> 1)) * 16384 +               \
                     ((wn & 1) * 64 + l16) * 128;                                   \
    int4v a00 = *(const int4v*)(aB + (2 * (p_)) * 2048 + q0);                       \
    int4v a01 = *(const int4v*)(aB + (2 * (p_)) * 2048 + q1);                       \
    int4v a10 = *(const int4v*)(aB + (2 * (p_) + 1) * 2048 + q0);                   \
    int4v a11 = *(const int4v*)(aB + (2 * (p_) + 1) * 2048 + q1);                   \
    if ((p_) == 0) {                                                                \
      _Pragma("unroll")                                                             \
      for (int wc = 0; wc < 4; ++wc) {                                              \
        bF[wc][0] = *(const int4v*)(bB + wc * 2048 + q0);                           \
        bF[wc][1] = *(const int4v*)(bB + wc * 2048 + q1);                           \
      }                                                                             \
    }                                                                               \
    if ((p_) == 0 && (tt) + 1 < nt) STAGE_A((tt) + 1, 0);                           \
    if ((p_) == 1 && (tt) + 1 < nt) STAGE_A((tt) + 1, 1);                           \
    if ((p_) == 2 && (tt) + 2 < nt) STAGE_B((tt) + 2, 0);                           \
    if ((p_) == 3 && (tt) + 2 < nt) STAGE_B((tt) + 2, 1);                           \
    __builtin_amdgcn_s_setprio(1);                                                  \
    _Pragma("unroll")                                                               \
    for (int wc = 0; wc < 4; ++wc) {                                                \
      acc[2 * (p_)][wc] =                                                           \
          __builtin_amdgcn_mfma_i32_16x16x64_i8(a00, bF[wc][0], acc[2 * (p_)][wc], 0, 0, 0); \
      acc[2 * (p_)][wc] =                                                           \
          __builtin_amdgcn_mfma_i32_16x16x64_i8(a01, bF[wc][1], acc[2 * (p_)][wc], 0, 0, 0); \
      acc[2 * (p_) + 1][wc] =                                                       \
          __builtin_amdgcn_mfma_i32_16x16x64_i8(a10, bF[wc][0], acc[2 * (p_) + 1][wc], 0, 0, 0); \
      acc[2 * (p_) + 1][wc] =                                                       \
          __builtin_amdgcn_mfma_i32_16x16x64_i8(a11, bF[wc][1], acc[2 * (p_) + 1][wc], 0, 0, 0); \
    }                                                                               \
    __builtin_amdgcn_s_setprio(0);                                                  \
  }

  STAGE_A(0, 0); STAGE_A(0, 1); STAGE_B(0, 0); STAGE_B(0, 1);
  STAGE_B(1, 0); STAGE_B(1, 1);

  int t = 0;
  for (; t + 1 < nt; t += 2) {
    PHASE(t, 0, 0) PHASE(t, 0, 1) PHASE(t, 0, 2) PHASE(t, 0, 3)
    PHASE(t + 1, 1, 0) PHASE(t + 1, 1, 1) PHASE(t + 1, 1, 2) PHASE(t + 1, 1, 3)
  }
  if (t < nt) {
    const int c = t & 1;
    if (c == 0) { PHASE(t, 0, 0) PHASE(t, 0, 1) PHASE(t, 0, 2) PHASE(t, 0, 3) }
    else        { PHASE(t, 1, 0) PHASE(t, 1, 1) PHASE(t, 1, 2) PHASE(t, 1, 3) }
  }
#undef STAGE_A
#undef STAGE_B
#undef PHASE

  // epilogue: C/D mapping dtype-independent: row=(lane>>4)*4+r, col=lane&15
#pragma unroll
  for (int fr = 0; fr < 8; ++fr) {
    const int rbase = tm + wm * 128 + fr * 16 + lk * 4;
    float rin[4];
    if constexpr (EPI == 5) {
#pragma unroll
      for (int r = 0; r < 4; ++r)
        rin[r] = kdq / biasv[(size_t)zz * ldbm + rbase + r];
    }
    float rs[4] = {0.f, 0.f, 0.f, 0.f};
#pragma unroll
    for (int wc = 0; wc < 4; ++wc) {
      const int col = tn + wn * 64 + wc * 16 + l16;
#pragma unroll
      for (int r = 0; r < 4; ++r) {
        const int row = rbase + r;
        if constexpr (EPI == 4) {
          float v = (float)acc[fr][wc][r] * kdq;
          v = __expf(v + bf2f(biasm[(size_t)row * ldbm + col]) +
                     biasv[(size_t)zz * T_DIM + col]);
          int q = (int)(v * qp + 0.5f);
          q = q > 127 ? 127 : q;
          C[(size_t)row * ldc + col] = (OutT)(signed char)q;
          rs[r] += (float)q;
        } else if constexpr (EPI == 5) {
          float v = (float)acc[fr][wc][r] * rin[r];
          storeC(&C[(size_t)row * ldc + col], v);
        }
      }
    }
    if constexpr (EPI == 4) {
#pragma unroll
      for (int r = 0; r < 4; ++r) {
#pragma unroll
        for (int off = 1; off < 16; off <<= 1) rs[r] += __shfl_xor(rs[r], off);
      }
      if (l16 == 0) {
        const int slab = ((zz * 8 + (tn >> 8)) * 4 + wn);
#pragma unroll
        for (int r = 0; r < 4; ++r)
          psum[(size_t)slab * 2048 + rbase + r] = rs[r];
      }
    }
  }
}

// ---------------- launch ----------------
extern "C" void kernel_launch(void* const* d_in, const int* in_sizes, int n_in,
                              void* d_out, int out_size, void* d_ws, size_t ws_size,
                              hipStream_t stream) {
  const float* x = (const float*)d_in[0];     // [8,2048,1024]
  const float* bias = (const float*)d_in[1];  // [2048,2048] fp32
  const float* Wqkv = (const float*)d_in[2];  // [3072,1024]  (Wq|Wk|Wv)
  const float* bqkv = (const float*)d_in[3];  // [3072]       (bq|bk|bv)
  const float* Wout = (const float*)d_in[4];  // [1024,1024]
  const float* bout = (const float*)d_in[5];  // [1024]
  float* out = (float*)d_out;                 // [8,2048,1024] fp32

  char* ws = (char*)d_ws;
  unsigned short* Xb    = (unsigned short*)(ws + 0);          // 33.5MB; reused as Valb
  signed char*    Xb8   = (signed char*)(ws + 33554432);      // 16.8MB i8 [16384,1024]
  signed char*    XT8   = (signed char*)(ws + 50331648);      // 16.8MB i8 [1024,16384]
  unsigned short* WqT   = (unsigned short*)(ws + 67108864);   // 2.1MB
  unsigned short* WkT   = (unsigned short*)(ws + 69206016);   // 2.1MB
  unsigned short* WvT   = (unsigned short*)(ws + 71303168);   // 2.1MB
  unsigned short* Woutb = (unsigned short*)(ws + 73400320);   // 2.1MB
  unsigned short* BH    = (unsigned short*)(ws + 75497472);   // 2.1MB (Wk^T Wq/32)^T
  unsigned short* Wfb   = (unsigned short*)(ws + 77594624);   // 2.1MB Wout*Wv
  float*          bfv   = (float*)(ws + 79691776);            // 4KB
  float*          a2    = (float*)(ws + 79695872);            // 4KB
  float*          wv    = (float*)(ws + 79699968);            // 64KB [8,2048]
  signed char*    Y8    = (signed char*)(ws + 79765504);      // 16.8MB i8 [16384,1024]
  unsigned short* biasb = (unsigned short*)(ws + 96542720);   // 8.4MB bf16
  signed char*    P8    = (signed char*)(ws + 104931328);     // 33.5MB i8 [8,2048,2048]
  float*          pw    = (float*)(ws + 104931328);           // 33.5MB splitK partials (pre-P8)
  float*          psum  = (float*)(ws + 138485760);           // 2MB [8][32][2048]
  unsigned short* Valb  = Xb;                                 // overlays Xb (dead after Y-GEMM)
  float*          R     = out + ((size_t)out_size - B_DIM * T_DIM);  // out tail scratch

  const long long sX8  = (long long)T_DIM * 1024;   // i8 per-batch stride (Y8/Xb8)
  const long long sTT8 = (long long)T_DIM * T_DIM;  // P8 batch stride
  const long long sTE  = (long long)T_DIM * E_DIM;

  // 1) conversions (x -> bf16 + i8 + i8-transposed; weights incl. Wout; bias)
  cvt_x_dual<<<dim3(256, 16), 256, 0, stream>>>(x, Xb, Xb8, XT8);
  cvt_w4<<<dim3(16, 16, 4), 256, 0, stream>>>(Wqkv, Wout, WqT, WkT, WvT, Woutb);
  cvt_bf16<<<4096, 256, 0, stream>>>((const float4*)bias, (ushort4*)biasb);

  // 2) small fused constants
  dotrows2<<<dim3(256, 2), 256, 0, stream>>>(Woutb, bqkv + 2048, bout, bfv,
                                             WkT, bqkv, a2);
  gemm128sk<<<dim3(8, 8, 8), 256, 0, stream>>>(WkT, WqT, Woutb, WvT, pw);
  finish_w<<<dim3(2048, 2), 256, 0, stream>>>(pw, BH, Wfb);
  wvec_k<<<4096, 256, 0, stream>>>(Xb, a2, wv);

  // 3) Y = X*H (bf16 in, i8 out at scale QY)
  gemm8p<6, signed char><<<dim3(64, 4, 1), 512, 0, stream>>>(
      Xb, 1024, 0, BH, 1024, 0, Y8, 1024, 0, 1024, nullptr, QY);

  // 4) logits (i8 x i8 -> i32): P8 = round(exp(acc*kdq + bias + wv)*QP), + psum
  gemm8i<4, signed char><<<dim3(8, 8, B_DIM), 512, 0, stream>>>(
      Y8, 1024, sX8, Xb8, 1024, sX8, P8, T_DIM, sTT8, 1024,
      wv, biasb, T_DIM, KDQ_LOGIT, QP, psum);

  // 5) R[z,t] = sum_s P8  (P-scale cancels in the normalization)
  finish_rowsum<<<dim3(8, B_DIM), 256, 0, stream>>>(psum, R);

  // 6) PV (i8 x i8): Val = (sum_s P8*X8) * (4/127) / R   (bf16 out)
  gemm8i<5, unsigned short><<<dim3(8, 4, B_DIM), 512, 0, stream>>>(
      P8, T_DIM, sTT8, XT8, 8 * T_DIM, T_DIM,
      Valb, E_DIM, sTE, T_DIM, R, nullptr, T_DIM, KDQ_PV, 0.f, nullptr);

  // 7) fused output projection: out = Val*Wf^T + bfv
  gemm8p<1, float><<<dim3(64, 4, 1), 512, 0, stream>>>(
      Valb, 1024, 0, Wfb, 1024, 0, out, 1024, 0, 1024, bfv, 0.f);
}